// Round 15
// baseline (5166.723 us; speedup 1.0000x reference)
//
#include <hip/hip_runtime.h>
#include <hip/hip_bf16.h>
#include <stdint.h>

#define TT 512
#define HD 512
#define BB 32
#define MM (BB*TT)     // 16384 rows (b*T+t)
#define NG 3072        // 2 dirs * 3 gates * 512
#define WGD 16         // workgroups per direction
#define CPW 32         // h columns per workgroup

typedef short short8 __attribute__((ext_vector_type(8)));
typedef float f32x4 __attribute__((ext_vector_type(4)));
typedef float f32x2 __attribute__((ext_vector_type(2)));
typedef unsigned short u16;
typedef unsigned int u32;
typedef unsigned long long u64;

__device__ __forceinline__ u16 f2bf(float f) {
  __hip_bfloat16 h = __float2bfloat16(f);
  union { __hip_bfloat16 h; u16 u; } c; c.h = h; return c.u;
}
__device__ __forceinline__ float bf2f(u16 u) {
  union { u32 i; float f; } c; c.i = ((u32)u) << 16; return c.f;
}
__device__ __forceinline__ float sigmf(float x) {
  return 1.0f / (1.0f + __expf(-x));
}
__device__ __forceinline__ float tanhff(float x) {
  float a = __expf(2.0f * x);          // inf -> 1, 0 -> -1 : graceful
  return 1.0f - 2.0f / (a + 1.0f);
}

// ---------------- f32 -> bf16 convert ----------------
__global__ __launch_bounds__(256) void cvt_bf16(const float* __restrict__ in,
                                                u16* __restrict__ out, int n8) {
  int i = blockIdx.x * 256 + threadIdx.x;
  if (i >= n8) return;
  const float4* p = (const float4*)in;
  float4 a = p[2*i], b = p[2*i+1];
  union { short8 v; u16 u[8]; } o;
  o.u[0]=f2bf(a.x); o.u[1]=f2bf(a.y); o.u[2]=f2bf(a.z); o.u[3]=f2bf(a.w);
  o.u[4]=f2bf(b.x); o.u[5]=f2bf(b.y); o.u[6]=f2bf(b.z); o.u[7]=f2bf(b.w);
  ((short8*)out)[i] = o.v;
}

// ---------------- gx GEMM (unchanged) ----------------
__global__ __launch_bounds__(256) void gemm_gx(const u16* __restrict__ A,
                                               const u16* __restrict__ Bw,
                                               char* __restrict__ gxout,
                                               int K, int gxf32) {
  __shared__ __align__(16) u16 lA[128*32];
  __shared__ __align__(16) u16 lB[128*32];
  const int tid = threadIdx.x;
  const int lane = tid & 63;
  const int wid = tid >> 6;
  const int wr = wid >> 1, wc = wid & 1;
  const int bm = blockIdx.y * 128, bn = blockIdx.x * 128;
  const int col = lane & 15, kg = lane >> 4;

  f32x4 acc[4][4];
#pragma unroll
  for (int m = 0; m < 4; ++m)
#pragma unroll
    for (int n = 0; n < 4; ++n) acc[m][n] = (f32x4){0.f,0.f,0.f,0.f};

  const int nkt = K >> 5;
  for (int kt = 0; kt < nkt; ++kt) {
    short8 ra[2], rb[2];
    const int kb = kt * 32;
#pragma unroll
    for (int p = 0; p < 2; ++p) {
      int id = p*256 + tid;
      int row = id >> 2, c = id & 3;
      ra[p] = *(const short8*)(A  + (size_t)(bm+row)*K + kb + c*8);
      rb[p] = *(const short8*)(Bw + (size_t)(bn+row)*K + kb + c*8);
    }
    __syncthreads();
#pragma unroll
    for (int p = 0; p < 2; ++p) {
      int id = p*256 + tid;
      int row = id >> 2, c = id & 3;
      int off = row*64 + ((c ^ ((row>>1)&3))*16);
      *(short8*)((char*)lA + off) = ra[p];
      *(short8*)((char*)lB + off) = rb[p];
    }
    __syncthreads();
    short8 af[4], bf[4];
#pragma unroll
    for (int m = 0; m < 4; ++m) {
      int row = wr*64 + m*16 + col;
      af[m] = *(short8*)((char*)lA + row*64 + ((kg ^ ((row>>1)&3))*16));
    }
#pragma unroll
    for (int n = 0; n < 4; ++n) {
      int row = wc*64 + n*16 + col;
      bf[n] = *(short8*)((char*)lB + row*64 + ((kg ^ ((row>>1)&3))*16));
    }
#pragma unroll
    for (int m = 0; m < 4; ++m)
#pragma unroll
      for (int n = 0; n < 4; ++n)
        acc[m][n] = __builtin_amdgcn_mfma_f32_16x16x32_bf16(af[m], bf[n], acc[m][n], 0,0,0);
  }
#pragma unroll
  for (int m = 0; m < 4; ++m)
#pragma unroll
    for (int n = 0; n < 4; ++n)
#pragma unroll
      for (int r = 0; r < 4; ++r) {
        int rowg = bm + wr*64 + m*16 + kg*4 + r;
        int colg = bn + wc*64 + n*16 + col;
        float v = acc[m][n][r];
        if (gxf32) ((float*)gxout)[(size_t)rowg*NG + colg] = v;
        else       ((u16*)gxout)[(size_t)rowg*NG + colg] = f2bf(v);
      }
}

// ---------------- persistent BiGRU recurrence (LDS dataflow, no barrier B) -----
// grid = 32 WGs (512 thr, 8 waves): dir = wg>>4, jb = wg&15 -> cols [jb*32,+32).
// Producer p's slice = h cols [32p,+32) = MFMA K-chunk kc=p exactly. Staging
// wave w handles producers p=w, p=w+8: LLC-poll flag, read 2KB slice, swizzle
// into parity-double-buffered hstage[par], lgkmcnt(0), set LDS flag
// done[par][p]=t+1. MFMA waves process kc-groups of 4, spinning on a cheap
// 4-flag LDS read -- early chunks compute while stragglers publish (jitter
// absorbed). Barrier B deleted; barrier C (gh) is the only full-WG sync, and
// it protects same-parity hstage reuse (2 steps apart). Plain out stores (R14).
__global__ __launch_bounds__(512, 2) void bigru_rec(const char* __restrict__ gx,
                                                    const u16* __restrict__ whhb,
                                                    const float* __restrict__ b_ih,
                                                    const float* __restrict__ b_hh,
                                                    char* __restrict__ out,
                                                    u16* __restrict__ himg,   // [2][2][32][512]
                                                    u32* __restrict__ flags,  // [2][16] stride 16 dwords
                                                    int gxf32, int outf32) {
  const int wg = blockIdx.x;
  const int dir = wg >> 4;
  const int jb = wg & 15;
  const int tid = threadIdx.x;
  const int lane = tid & 63;
  const int wv = tid >> 6;
  const int col = lane & 15, kg = lane >> 4;

  __shared__ __align__(16) u16 hstage[2][32*512];  // 64 KB, parity dbuf, swizzled
  __shared__ float gh[3][32][33];                  // padded: no bank conflicts
  __shared__ float bihs[3][32], bhhs[3][32];
  __shared__ u32 done[2][16];                      // LDS chunk flags (tag = t+1)
  __shared__ u32 lctr;

  // --- one-time: w_hh B-fragments (waves 0..5: gate g=wv>>1, half ch=wv&1) ---
  short8 bfrag[16];
  if (wv < 6) {
    const int g = wv >> 1, ch = wv & 1;
    const u16* wrow = whhb + (size_t)(dir*1536 + g*512 + jb*CPW + ch*16 + col) * 512;
#pragma unroll
    for (int kc = 0; kc < 16; ++kc)
      bfrag[kc] = *(const short8*)(wrow + kc*32 + kg*8);
  }
  if (tid < 96) {
    int g = tid >> 5, j = tid & 31;
    bihs[g][j] = b_ih[dir*1536 + g*512 + jb*CPW + j];
    bhhs[g][j] = b_hh[dir*1536 + g*512 + jb*CPW + j];
  }
  if (tid < 32) done[tid >> 4][tid & 15] = 0;
  if (tid == 0) lctr = 0;
  __syncthreads();

  const int gb = tid >> 4, gj0 = (tid & 15) * 2;
  float hp0 = 0.f, hp1 = 0.f;

  u32* dirflags = flags + (size_t)dir * WGD * 16;
  u32* myflag = dirflags + (size_t)jb * 16;

  // slice-read lane mapping: row = lane>>1, 32B group g4 = (lane&1)*4
  const int srow = lane >> 1, sg4 = (lane & 1) * 4;
  const int p0 = wv, p1 = wv + 8;
  const u32* fp0 = dirflags + (size_t)p0 * 16;
  const u32* fp1 = dirflags + (size_t)p1 * 16;

  for (int t = 0; t < TT; ++t) {
    const int tt = dir ? (TT - 1 - t) : t;
    const int par = t & 1;
    char* hstg = (char*)hstage[par];

    // --- gx[tt] -> registers (issued early; retire under poll) ---
    f32x2 xrF, xzF, xnF; u32 xrB=0, xzB=0, xnB=0;
    if (gxf32) {
      const float* gp = (const float*)gx + (size_t)(gb*TT+tt)*NG + dir*1536 + jb*CPW + gj0;
      xrF = *(const f32x2*)(gp);
      xzF = *(const f32x2*)(gp + 512);
      xnF = *(const f32x2*)(gp + 1024);
    } else {
      const u16* gp = (const u16*)gx + (size_t)(gb*TT+tt)*NG + dir*1536 + jb*CPW + gj0;
      xrB = *(const u32*)(gp);
      xzB = *(const u32*)(gp + 512);
      xnB = *(const u32*)(gp + 1024);
    }

    // --- stage producer p0: LLC poll -> slice read -> swizzled LDS -> flag ---
    const u64* imgr = (const u64*)(himg + ((size_t)dir*2 + par) * 32 * 512);
    {
      if (t > 0) {
        const u32 need = (u32)t;
        int it = 0;
        while (__hip_atomic_load(fp0, __ATOMIC_RELAXED, __HIP_MEMORY_SCOPE_AGENT) < need && it++ < (1<<24)) {}
      }
      __builtin_amdgcn_sched_barrier(0);
      asm volatile("" ::: "memory");
      u64 v[4];
#pragma unroll
      for (int j = 0; j < 4; ++j)
        v[j] = __hip_atomic_load(imgr + srow*128 + p0*8 + sg4 + j, __ATOMIC_RELAXED, __HIP_MEMORY_SCOPE_AGENT);
#pragma unroll
      for (int j = 0; j < 4; ++j) {
        int d2 = p0*8 + sg4 + j; int c = d2 >> 1;
        *(u64*)(hstg + srow*1024 + (((c ^ (srow & 7)) << 4) | ((d2 & 1) << 3))) = v[j];
      }
      asm volatile("s_waitcnt lgkmcnt(0)" ::: "memory");
      if (lane == 0) *(volatile u32*)&done[par][p0] = (u32)(t + 1);
    }
    // --- stage producer p1 ---
    {
      if (t > 0) {
        const u32 need = (u32)t;
        int it = 0;
        while (__hip_atomic_load(fp1, __ATOMIC_RELAXED, __HIP_MEMORY_SCOPE_AGENT) < need && it++ < (1<<24)) {}
      }
      __builtin_amdgcn_sched_barrier(0);
      asm volatile("" ::: "memory");
      u64 v[4];
#pragma unroll
      for (int j = 0; j < 4; ++j)
        v[j] = __hip_atomic_load(imgr + srow*128 + p1*8 + sg4 + j, __ATOMIC_RELAXED, __HIP_MEMORY_SCOPE_AGENT);
#pragma unroll
      for (int j = 0; j < 4; ++j) {
        int d2 = p1*8 + sg4 + j; int c = d2 >> 1;
        *(u64*)(hstg + srow*1024 + (((c ^ (srow & 7)) << 4) | ((d2 & 1) << 3))) = v[j];
      }
      asm volatile("s_waitcnt lgkmcnt(0)" ::: "memory");
      if (lane == 0) *(volatile u32*)&done[par][p1] = (u32)(t + 1);
    }

    // --- MFMA: kc-groups of 4, LDS dataflow spin (no barrier B) ---
    if (wv < 6) {
      const int g = wv >> 1, ch = wv & 1;
      f32x4 acc0 = (f32x4){0.f,0.f,0.f,0.f};
      f32x4 acc1 = (f32x4){0.f,0.f,0.f,0.f};
      const u32 need = (u32)(t + 1);
#pragma unroll
      for (int grp = 0; grp < 4; ++grp) {
        // spin: 4 chunk flags (one 16B LDS read when already set)
        {
          const volatile u32* dn = &done[par][grp*4];
          int it = 0;
          while (it++ < (1<<24)) {
            u32 d0 = dn[0], d1 = dn[1], d2 = dn[2], d3 = dn[3];
            if (d0 >= need && d1 >= need && d2 >= need && d3 >= need) break;
          }
        }
        __builtin_amdgcn_sched_barrier(0);
        asm volatile("" ::: "memory");   // pin A-frag reads AFTER the spin
#pragma unroll
        for (int kq = 0; kq < 4; ++kq) {
          int kc = grp*4 + kq;
          int c = kc*4 + kg;
          short8 a0 = *(short8*)(hstg + col*1024      + ((c ^ (col & 7)) << 4));
          short8 a1 = *(short8*)(hstg + (16+col)*1024 + ((c ^ (col & 7)) << 4));
          acc0 = __builtin_amdgcn_mfma_f32_16x16x32_bf16(a0, bfrag[kc], acc0, 0,0,0);
          acc1 = __builtin_amdgcn_mfma_f32_16x16x32_bf16(a1, bfrag[kc], acc1, 0,0,0);
        }
      }
#pragma unroll
      for (int r = 0; r < 4; ++r) {
        gh[g][kg*4 + r][ch*16 + col]      = acc0[r];
        gh[g][16 + kg*4 + r][ch*16 + col] = acc1[r];
      }
    }
    __syncthreads();   // (C) gh ready; also fences same-parity hstage reuse

    // --- gates: thread -> (b=gb, j=gj0, gj0+1) ---
    float hv0, hv1; u32 pv;
    {
      float xr0, xz0, xn0, xr1, xz1, xn1;
      if (gxf32) {
        xr0 = xrF.x; xz0 = xzF.x; xn0 = xnF.x;
        xr1 = xrF.y; xz1 = xzF.y; xn1 = xnF.y;
      } else {
        xr0 = bf2f((u16)(xrB & 0xffff)); xz0 = bf2f((u16)(xzB & 0xffff)); xn0 = bf2f((u16)(xnB & 0xffff));
        xr1 = bf2f((u16)(xrB >> 16));    xz1 = bf2f((u16)(xzB >> 16));    xn1 = bf2f((u16)(xnB >> 16));
      }
      float r0 = sigmf(xr0 + bihs[0][gj0]   + gh[0][gb][gj0]   + bhhs[0][gj0]);
      float z0 = sigmf(xz0 + bihs[1][gj0]   + gh[1][gb][gj0]   + bhhs[1][gj0]);
      float n0 = tanhff(xn0 + bihs[2][gj0]  + r0*(gh[2][gb][gj0] + bhhs[2][gj0]));
      hv0 = (1.f - z0)*n0 + z0*hp0;
      float r1 = sigmf(xr1 + bihs[0][gj0+1] + gh[0][gb][gj0+1] + bhhs[0][gj0+1]);
      float z1 = sigmf(xz1 + bihs[1][gj0+1] + gh[1][gb][gj0+1] + bhhs[1][gj0+1]);
      float n1 = tanhff(xn1 + bihs[2][gj0+1] + r1*(gh[2][gb][gj0+1] + bhhs[2][gj0+1]));
      hv1 = (1.f - z1)*n1 + z1*hp1;
      hp0 = hv0; hp1 = hv1;

      // publish h_new pair to next image (agent -> LLC)
      u32* img2 = (u32*)(himg + ((size_t)dir*2 + ((t + 1) & 1)) * 32 * 512);
      pv = (u32)f2bf(hv0) | ((u32)f2bf(hv1) << 16);
      __hip_atomic_store(img2 + gb*256 + jb*16 + (tid & 15), pv,
                         __ATOMIC_RELAXED, __HIP_MEMORY_SCOPE_AGENT);
    }

    // --- per-wave drain (parallel) -> LDS counter -> 8th wave releases WG flag ---
    asm volatile("s_waitcnt vmcnt(0)" ::: "memory");
    if (lane == 0) {
      u32 old = atomicAdd(&lctr, 1u);
      if (old == (u32)(t*8 + 7))
        __hip_atomic_store(myflag, (u32)(t + 1), __ATOMIC_RELAXED, __HIP_MEMORY_SCOPE_AGENT);
    }

    // --- out store after flag: plain cached store (L2 ack; R14 win) ---
    {
      size_t oi = (size_t)(gb*TT + tt)*1024 + dir*512 + jb*CPW + gj0;
      if (outf32) {
        f32x2 ov; ov.x = hv0; ov.y = hv1;
        *(f32x2*)((float*)out + oi) = ov;
      } else {
        *(u32*)((u16*)out + oi) = pv;
      }
    }
  }
}

// ---------------- host ----------------
extern "C" void kernel_launch(void* const* d_in, const int* in_sizes, int n_in,
                              void* d_out, int out_size, void* d_ws, size_t ws_size,
                              hipStream_t stream) {
  (void)in_sizes; (void)n_in; (void)out_size;
  const float* x    = (const float*)d_in[0];
  const float* wih0 = (const float*)d_in[1];
  const float* whh0 = (const float*)d_in[2];
  const float* bih0 = (const float*)d_in[3];
  const float* bhh0 = (const float*)d_in[4];
  const float* wih1 = (const float*)d_in[5];
  const float* whh1 = (const float*)d_in[6];
  const float* bih1 = (const float*)d_in[7];
  const float* bhh1 = (const float*)d_in[8];

  char* ws = (char*)d_ws;
  size_t off = 0;
  auto alloc = [&](size_t bytes) { size_t o = off; off += (bytes + 255) & ~(size_t)255; return o; };
  size_t off_xb   = alloc((size_t)MM * 512 * 2);       // x bf16
  size_t off_wih0 = alloc((size_t)3072 * 512 * 2);
  size_t off_wih1 = alloc((size_t)3072 * 1024 * 2);
  size_t off_whh0 = alloc((size_t)3072 * 512 * 2);
  size_t off_whh1 = alloc((size_t)3072 * 512 * 2);
  size_t off_h0   = alloc((size_t)MM * 1024 * 2);      // layer-0 output bf16
  size_t off_sync = alloc(131072 + 4096);              // h images (128KB) + flags
  size_t off_gx   = off;                               // gx last
  int gxf32 = (ws_size >= off_gx + (size_t)MM * NG * 4) ? 1 : 0;

  u16* xb    = (u16*)(ws + off_xb);
  u16* wih0b = (u16*)(ws + off_wih0);
  u16* wih1b = (u16*)(ws + off_wih1);
  u16* whh0b = (u16*)(ws + off_whh0);
  u16* whh1b = (u16*)(ws + off_whh1);
  u16* h0b   = (u16*)(ws + off_h0);
  u16* himg  = (u16*)(ws + off_sync);
  u32* flags = (u32*)(ws + off_sync + 131072);
  char* gx   = ws + off_gx;

  cvt_bf16<<<4096, 256, 0, stream>>>(x,    xb,    MM*512/8);
  cvt_bf16<<<768,  256, 0, stream>>>(wih0, wih0b, 3072*512/8);
  cvt_bf16<<<1536, 256, 0, stream>>>(wih1, wih1b, 3072*1024/8);
  cvt_bf16<<<768,  256, 0, stream>>>(whh0, whh0b, 3072*512/8);
  cvt_bf16<<<768,  256, 0, stream>>>(whh1, whh1b, 3072*512/8);

  dim3 ggrid(NG/128, MM/128);   // (24, 128)

  // layer 0
  gemm_gx<<<ggrid, 256, 0, stream>>>(xb, wih0b, gx, 512, gxf32);
  (void)hipMemsetAsync(ws + off_sync, 0, 131072 + 4096, stream);
  bigru_rec<<<32, 512, 0, stream>>>(gx, whh0b, bih0, bhh0, (char*)h0b, himg, flags, gxf32, 0);

  // layer 1
  gemm_gx<<<ggrid, 256, 0, stream>>>(h0b, wih1b, gx, 1024, gxf32);
  (void)hipMemsetAsync(ws + off_sync, 0, 131072 + 4096, stream);
  bigru_rec<<<32, 512, 0, stream>>>(gx, whh1b, bih1, bhh1, (char*)d_out, himg, flags, gxf32, 1);
}

// Round 16
// 4887.648 us; speedup vs baseline: 1.0571x; 1.0571x over previous
//
#include <hip/hip_runtime.h>
#include <hip/hip_bf16.h>
#include <stdint.h>

#define TT 512
#define HD 512
#define BB 32
#define MM (BB*TT)     // 16384 rows (b*T+t)
#define NG 3072        // 2 dirs * 3 gates * 512
#define WGD 16         // workgroups per direction
#define CPW 32         // h columns per workgroup

typedef short short8 __attribute__((ext_vector_type(8)));
typedef float f32x4 __attribute__((ext_vector_type(4)));
typedef float f32x2 __attribute__((ext_vector_type(2)));
typedef unsigned short u16;
typedef unsigned int u32;
typedef unsigned long long u64;

__device__ __forceinline__ u16 f2bf(float f) {
  __hip_bfloat16 h = __float2bfloat16(f);
  union { __hip_bfloat16 h; u16 u; } c; c.h = h; return c.u;
}
__device__ __forceinline__ float bf2f(u16 u) {
  union { u32 i; float f; } c; c.i = ((u32)u) << 16; return c.f;
}
__device__ __forceinline__ float sigmf(float x) {
  return 1.0f / (1.0f + __expf(-x));
}
__device__ __forceinline__ float tanhff(float x) {
  float a = __expf(2.0f * x);          // inf -> 1, 0 -> -1 : graceful
  return 1.0f - 2.0f / (a + 1.0f);
}

// ---------------- f32 -> bf16 convert ----------------
__global__ __launch_bounds__(256) void cvt_bf16(const float* __restrict__ in,
                                                u16* __restrict__ out, int n8) {
  int i = blockIdx.x * 256 + threadIdx.x;
  if (i >= n8) return;
  const float4* p = (const float4*)in;
  float4 a = p[2*i], b = p[2*i+1];
  union { short8 v; u16 u[8]; } o;
  o.u[0]=f2bf(a.x); o.u[1]=f2bf(a.y); o.u[2]=f2bf(a.z); o.u[3]=f2bf(a.w);
  o.u[4]=f2bf(b.x); o.u[5]=f2bf(b.y); o.u[6]=f2bf(b.z); o.u[7]=f2bf(b.w);
  ((short8*)out)[i] = o.v;
}

// ---------------- gx GEMM (unchanged) ----------------
__global__ __launch_bounds__(256) void gemm_gx(const u16* __restrict__ A,
                                               const u16* __restrict__ Bw,
                                               char* __restrict__ gxout,
                                               int K, int gxf32) {
  __shared__ __align__(16) u16 lA[128*32];
  __shared__ __align__(16) u16 lB[128*32];
  const int tid = threadIdx.x;
  const int lane = tid & 63;
  const int wid = tid >> 6;
  const int wr = wid >> 1, wc = wid & 1;
  const int bm = blockIdx.y * 128, bn = blockIdx.x * 128;
  const int col = lane & 15, kg = lane >> 4;

  f32x4 acc[4][4];
#pragma unroll
  for (int m = 0; m < 4; ++m)
#pragma unroll
    for (int n = 0; n < 4; ++n) acc[m][n] = (f32x4){0.f,0.f,0.f,0.f};

  const int nkt = K >> 5;
  for (int kt = 0; kt < nkt; ++kt) {
    short8 ra[2], rb[2];
    const int kb = kt * 32;
#pragma unroll
    for (int p = 0; p < 2; ++p) {
      int id = p*256 + tid;
      int row = id >> 2, c = id & 3;
      ra[p] = *(const short8*)(A  + (size_t)(bm+row)*K + kb + c*8);
      rb[p] = *(const short8*)(Bw + (size_t)(bn+row)*K + kb + c*8);
    }
    __syncthreads();
#pragma unroll
    for (int p = 0; p < 2; ++p) {
      int id = p*256 + tid;
      int row = id >> 2, c = id & 3;
      int off = row*64 + ((c ^ ((row>>1)&3))*16);
      *(short8*)((char*)lA + off) = ra[p];
      *(short8*)((char*)lB + off) = rb[p];
    }
    __syncthreads();
    short8 af[4], bf[4];
#pragma unroll
    for (int m = 0; m < 4; ++m) {
      int row = wr*64 + m*16 + col;
      af[m] = *(short8*)((char*)lA + row*64 + ((kg ^ ((row>>1)&3))*16));
    }
#pragma unroll
    for (int n = 0; n < 4; ++n) {
      int row = wc*64 + n*16 + col;
      bf[n] = *(short8*)((char*)lB + row*64 + ((kg ^ ((row>>1)&3))*16));
    }
#pragma unroll
    for (int m = 0; m < 4; ++m)
#pragma unroll
      for (int n = 0; n < 4; ++n)
        acc[m][n] = __builtin_amdgcn_mfma_f32_16x16x32_bf16(af[m], bf[n], acc[m][n], 0,0,0);
  }
#pragma unroll
  for (int m = 0; m < 4; ++m)
#pragma unroll
    for (int n = 0; n < 4; ++n)
#pragma unroll
      for (int r = 0; r < 4; ++r) {
        int rowg = bm + wr*64 + m*16 + kg*4 + r;
        int colg = bn + wc*64 + n*16 + col;
        float v = acc[m][n][r];
        if (gxf32) ((float*)gxout)[(size_t)rowg*NG + colg] = v;
        else       ((u16*)gxout)[(size_t)rowg*NG + colg] = f2bf(v);
      }
}

// ---------------- persistent BiGRU recurrence (R14 + pipelined poll) ----------
// grid = 32 WGs (512 thr, 8 waves): dir = wg>>4, jb = wg&15 -> cols [jb*32,+32).
// Wave w polls producers p=w and p=w+8 and reads each 2KB slice when its flag
// lands. NEW vs R14: the flag spin keeps 3 loads in flight (vmcnt retires in
// order -> checking the oldest samples the flag every ~RTT/3 instead of every
// RTT for a dependent spin), cutting detection delay. Everything else R14:
// plain cached out stores, parallel drain -> lctr -> WG flag, sched_barrier
// compiler fences pinning slice loads after the poll.
__global__ __launch_bounds__(512, 2) void bigru_rec(const char* __restrict__ gx,
                                                    const u16* __restrict__ whhb,
                                                    const float* __restrict__ b_ih,
                                                    const float* __restrict__ b_hh,
                                                    char* __restrict__ out,
                                                    u16* __restrict__ himg,   // [2][2][32][512]
                                                    u32* __restrict__ flags,  // [2][16] stride 16 dwords
                                                    int gxf32, int outf32) {
  const int wg = blockIdx.x;
  const int dir = wg >> 4;
  const int jb = wg & 15;
  const int tid = threadIdx.x;
  const int lane = tid & 63;
  const int wv = tid >> 6;
  const int col = lane & 15, kg = lane >> 4;

  __shared__ __align__(16) u16 hstage[32*512];     // 32 KB, swizzled
  __shared__ float gh[3][32][33];                  // padded: no bank conflicts
  __shared__ float bihs[3][32], bhhs[3][32];
  __shared__ u32 lctr;

  // --- one-time: w_hh B-fragments (waves 0..5: gate g=wv>>1, half ch=wv&1) ---
  short8 bfrag[16];
  if (wv < 6) {
    const int g = wv >> 1, ch = wv & 1;
    const u16* wrow = whhb + (size_t)(dir*1536 + g*512 + jb*CPW + ch*16 + col) * 512;
#pragma unroll
    for (int kc = 0; kc < 16; ++kc)
      bfrag[kc] = *(const short8*)(wrow + kc*32 + kg*8);
  }
  if (tid < 96) {
    int g = tid >> 5, j = tid & 31;
    bihs[g][j] = b_ih[dir*1536 + g*512 + jb*CPW + j];
    bhhs[g][j] = b_hh[dir*1536 + g*512 + jb*CPW + j];
  }
  if (tid == 0) lctr = 0;
  __syncthreads();

  const int gb = tid >> 4, gj0 = (tid & 15) * 2;
  float hp0 = 0.f, hp1 = 0.f;

  u32* dirflags = flags + (size_t)dir * WGD * 16;
  u32* myflag = dirflags + (size_t)jb * 16;

  // slice-read lane mapping: row = lane>>1, 32B group g4 = (lane&1)*4
  const int srow = lane >> 1, sg4 = (lane & 1) * 4;
  const int p0 = wv, p1 = wv + 8;
  const u32* fp0 = dirflags + (size_t)p0 * 16;
  const u32* fp1 = dirflags + (size_t)p1 * 16;

  for (int t = 0; t < TT; ++t) {
    const int tt = dir ? (TT - 1 - t) : t;
    const int par = t & 1;

    // --- gx[tt] -> registers (issued early; retire under poll) ---
    f32x2 xrF, xzF, xnF; u32 xrB=0, xzB=0, xnB=0;
    if (gxf32) {
      const float* gp = (const float*)gx + (size_t)(gb*TT+tt)*NG + dir*1536 + jb*CPW + gj0;
      xrF = *(const f32x2*)(gp);
      xzF = *(const f32x2*)(gp + 512);
      xnF = *(const f32x2*)(gp + 1024);
    } else {
      const u16* gp = (const u16*)gx + (size_t)(gb*TT+tt)*NG + dir*1536 + jb*CPW + gj0;
      xrB = *(const u32*)(gp);
      xzB = *(const u32*)(gp + 512);
      xnB = *(const u32*)(gp + 1024);
    }

    // --- pipelined per-producer poll + slice read (2KB each) ---
    const u64* imgr = (const u64*)(himg + ((size_t)dir*2 + par) * 32 * 512);
    u64 v0[4], v1[4];
    if (t > 0) {
      const u32 need = (u32)t;
      // 3-deep software-pipelined spin: check oldest sample, keep 3 in flight
      u32 a = __hip_atomic_load(fp0, __ATOMIC_RELAXED, __HIP_MEMORY_SCOPE_AGENT);
      u32 b = __hip_atomic_load(fp0, __ATOMIC_RELAXED, __HIP_MEMORY_SCOPE_AGENT);
      u32 c = __hip_atomic_load(fp0, __ATOMIC_RELAXED, __HIP_MEMORY_SCOPE_AGENT);
      int it = 0;
      while (a < need && it++ < (1 << 22)) {
        u32 d = __hip_atomic_load(fp0, __ATOMIC_RELAXED, __HIP_MEMORY_SCOPE_AGENT);
        a = b; b = c; c = d;
      }
    }
    __builtin_amdgcn_sched_barrier(0);
    asm volatile("" ::: "memory");   // pin slice loads AFTER the poll (compiler fence)
#pragma unroll
    for (int j = 0; j < 4; ++j)
      v0[j] = __hip_atomic_load(imgr + srow*128 + p0*8 + sg4 + j, __ATOMIC_RELAXED, __HIP_MEMORY_SCOPE_AGENT);
    if (t > 0) {
      const u32 need = (u32)t;
      u32 a = __hip_atomic_load(fp1, __ATOMIC_RELAXED, __HIP_MEMORY_SCOPE_AGENT);
      u32 b = __hip_atomic_load(fp1, __ATOMIC_RELAXED, __HIP_MEMORY_SCOPE_AGENT);
      u32 c = __hip_atomic_load(fp1, __ATOMIC_RELAXED, __HIP_MEMORY_SCOPE_AGENT);
      int it = 0;
      while (a < need && it++ < (1 << 22)) {
        u32 d = __hip_atomic_load(fp1, __ATOMIC_RELAXED, __HIP_MEMORY_SCOPE_AGENT);
        a = b; b = c; c = d;
      }
    }
    __builtin_amdgcn_sched_barrier(0);
    asm volatile("" ::: "memory");   // pin slice loads AFTER the poll (compiler fence)
#pragma unroll
    for (int j = 0; j < 4; ++j)
      v1[j] = __hip_atomic_load(imgr + srow*128 + p1*8 + sg4 + j, __ATOMIC_RELAXED, __HIP_MEMORY_SCOPE_AGENT);

    // --- LDS writes: slices (swizzled) ---
#pragma unroll
    for (int j = 0; j < 4; ++j) {
      int d2 = p0*8 + sg4 + j; int c = d2 >> 1;
      *(u64*)((char*)hstage + srow*1024 + (((c ^ (srow & 7)) << 4) | ((d2 & 1) << 3))) = v0[j];
    }
#pragma unroll
    for (int j = 0; j < 4; ++j) {
      int d2 = p1*8 + sg4 + j; int c = d2 >> 1;
      *(u64*)((char*)hstage + srow*1024 + (((c ^ (srow & 7)) << 4) | ((d2 & 1) << 3))) = v1[j];
    }
    __syncthreads();   // (B) hstage staged by all waves

    // --- MFMA: gh[g][b][jloc] over K=512 (waves 0..5) ---
    if (wv < 6) {
      const int g = wv >> 1, ch = wv & 1;
      f32x4 acc0 = (f32x4){0.f,0.f,0.f,0.f};
      f32x4 acc1 = (f32x4){0.f,0.f,0.f,0.f};
#pragma unroll
      for (int kc = 0; kc < 16; ++kc) {
        int c = kc*4 + kg;
        short8 a0 = *(short8*)((char*)hstage + col*1024      + ((c ^ (col & 7)) << 4));
        short8 a1 = *(short8*)((char*)hstage + (16+col)*1024 + ((c ^ (col & 7)) << 4));
        acc0 = __builtin_amdgcn_mfma_f32_16x16x32_bf16(a0, bfrag[kc], acc0, 0,0,0);
        acc1 = __builtin_amdgcn_mfma_f32_16x16x32_bf16(a1, bfrag[kc], acc1, 0,0,0);
      }
#pragma unroll
      for (int r = 0; r < 4; ++r) {
        gh[g][kg*4 + r][ch*16 + col]      = acc0[r];
        gh[g][16 + kg*4 + r][ch*16 + col] = acc1[r];
      }
    }
    __syncthreads();   // (C)

    // --- gates: thread -> (b=gb, j=gj0, gj0+1) ---
    float hv0, hv1; u32 pv;
    {
      float xr0, xz0, xn0, xr1, xz1, xn1;
      if (gxf32) {
        xr0 = xrF.x; xz0 = xzF.x; xn0 = xnF.x;
        xr1 = xrF.y; xz1 = xzF.y; xn1 = xnF.y;
      } else {
        xr0 = bf2f((u16)(xrB & 0xffff)); xz0 = bf2f((u16)(xzB & 0xffff)); xn0 = bf2f((u16)(xnB & 0xffff));
        xr1 = bf2f((u16)(xrB >> 16));    xz1 = bf2f((u16)(xzB >> 16));    xn1 = bf2f((u16)(xnB >> 16));
      }
      float r0 = sigmf(xr0 + bihs[0][gj0]   + gh[0][gb][gj0]   + bhhs[0][gj0]);
      float z0 = sigmf(xz0 + bihs[1][gj0]   + gh[1][gb][gj0]   + bhhs[1][gj0]);
      float n0 = tanhff(xn0 + bihs[2][gj0]  + r0*(gh[2][gb][gj0] + bhhs[2][gj0]));
      hv0 = (1.f - z0)*n0 + z0*hp0;
      float r1 = sigmf(xr1 + bihs[0][gj0+1] + gh[0][gb][gj0+1] + bhhs[0][gj0+1]);
      float z1 = sigmf(xz1 + bihs[1][gj0+1] + gh[1][gb][gj0+1] + bhhs[1][gj0+1]);
      float n1 = tanhff(xn1 + bihs[2][gj0+1] + r1*(gh[2][gb][gj0+1] + bhhs[2][gj0+1]));
      hv1 = (1.f - z1)*n1 + z1*hp1;
      hp0 = hv0; hp1 = hv1;

      // publish h_new pair to next image (agent -> LLC)
      u32* img2 = (u32*)(himg + ((size_t)dir*2 + ((t + 1) & 1)) * 32 * 512);
      pv = (u32)f2bf(hv0) | ((u32)f2bf(hv1) << 16);
      __hip_atomic_store(img2 + gb*256 + jb*16 + (tid & 15), pv,
                         __ATOMIC_RELAXED, __HIP_MEMORY_SCOPE_AGENT);
    }

    // --- per-wave drain (parallel) -> LDS counter -> 8th wave releases WG flag ---
    asm volatile("s_waitcnt vmcnt(0)" ::: "memory");
    if (lane == 0) {
      u32 old = atomicAdd(&lctr, 1u);
      if (old == (u32)(t*8 + 7))
        __hip_atomic_store(myflag, (u32)(t + 1), __ATOMIC_RELAXED, __HIP_MEMORY_SCOPE_AGENT);
    }

    // --- out store after flag: plain cached store (L2 ack; R14 win) ---
    {
      size_t oi = (size_t)(gb*TT + tt)*1024 + dir*512 + jb*CPW + gj0;
      if (outf32) {
        f32x2 ov; ov.x = hv0; ov.y = hv1;
        *(f32x2*)((float*)out + oi) = ov;
      } else {
        *(u32*)((u16*)out + oi) = pv;
      }
    }
  }
}

// ---------------- host ----------------
extern "C" void kernel_launch(void* const* d_in, const int* in_sizes, int n_in,
                              void* d_out, int out_size, void* d_ws, size_t ws_size,
                              hipStream_t stream) {
  (void)in_sizes; (void)n_in; (void)out_size;
  const float* x    = (const float*)d_in[0];
  const float* wih0 = (const float*)d_in[1];
  const float* whh0 = (const float*)d_in[2];
  const float* bih0 = (const float*)d_in[3];
  const float* bhh0 = (const float*)d_in[4];
  const float* wih1 = (const float*)d_in[5];
  const float* whh1 = (const float*)d_in[6];
  const float* bih1 = (const float*)d_in[7];
  const float* bhh1 = (const float*)d_in[8];

  char* ws = (char*)d_ws;
  size_t off = 0;
  auto alloc = [&](size_t bytes) { size_t o = off; off += (bytes + 255) & ~(size_t)255; return o; };
  size_t off_xb   = alloc((size_t)MM * 512 * 2);       // x bf16
  size_t off_wih0 = alloc((size_t)3072 * 512 * 2);
  size_t off_wih1 = alloc((size_t)3072 * 1024 * 2);
  size_t off_whh0 = alloc((size_t)3072 * 512 * 2);
  size_t off_whh1 = alloc((size_t)3072 * 512 * 2);
  size_t off_h0   = alloc((size_t)MM * 1024 * 2);      // layer-0 output bf16
  size_t off_sync = alloc(131072 + 4096);              // h images (128KB) + flags
  size_t off_gx   = off;                               // gx last
  int gxf32 = (ws_size >= off_gx + (size_t)MM * NG * 4) ? 1 : 0;

  u16* xb    = (u16*)(ws + off_xb);
  u16* wih0b = (u16*)(ws + off_wih0);
  u16* wih1b = (u16*)(ws + off_wih1);
  u16* whh0b = (u16*)(ws + off_whh0);
  u16* whh1b = (u16*)(ws + off_whh1);
  u16* h0b   = (u16*)(ws + off_h0);
  u16* himg  = (u16*)(ws + off_sync);
  u32* flags = (u32*)(ws + off_sync + 131072);
  char* gx   = ws + off_gx;

  cvt_bf16<<<4096, 256, 0, stream>>>(x,    xb,    MM*512/8);
  cvt_bf16<<<768,  256, 0, stream>>>(wih0, wih0b, 3072*512/8);
  cvt_bf16<<<1536, 256, 0, stream>>>(wih1, wih1b, 3072*1024/8);
  cvt_bf16<<<768,  256, 0, stream>>>(whh0, whh0b, 3072*512/8);
  cvt_bf16<<<768,  256, 0, stream>>>(whh1, whh1b, 3072*512/8);

  dim3 ggrid(NG/128, MM/128);   // (24, 128)

  // layer 0
  gemm_gx<<<ggrid, 256, 0, stream>>>(xb, wih0b, gx, 512, gxf32);
  (void)hipMemsetAsync(ws + off_sync, 0, 131072 + 4096, stream);
  bigru_rec<<<32, 512, 0, stream>>>(gx, whh0b, bih0, bhh0, (char*)h0b, himg, flags, gxf32, 0);

  // layer 1
  gemm_gx<<<ggrid, 256, 0, stream>>>(h0b, wih1b, gx, 1024, gxf32);
  (void)hipMemsetAsync(ws + off_sync, 0, 131072 + 4096, stream);
  bigru_rec<<<32, 512, 0, stream>>>(gx, whh1b, bih1, bhh1, (char*)d_out, himg, flags, gxf32, 1);
}

// Round 17
// 4581.199 us; speedup vs baseline: 1.1278x; 1.0669x over previous
//
#include <hip/hip_runtime.h>
#include <hip/hip_bf16.h>
#include <stdint.h>

#define TT 512
#define HD 512
#define BB 32
#define MM (BB*TT)     // 16384 rows (b*T+t)
#define NG 3072        // 2 dirs * 3 gates * 512
#define WGD 16         // workgroups per direction
#define CPW 32         // h columns per workgroup

typedef short short8 __attribute__((ext_vector_type(8)));
typedef float f32x4 __attribute__((ext_vector_type(4)));
typedef float f32x2 __attribute__((ext_vector_type(2)));
typedef unsigned short u16;
typedef unsigned int u32;
typedef unsigned long long u64;

__device__ __forceinline__ u16 f2bf(float f) {
  __hip_bfloat16 h = __float2bfloat16(f);
  union { __hip_bfloat16 h; u16 u; } c; c.h = h; return c.u;
}
__device__ __forceinline__ float bf2f(u16 u) {
  union { u32 i; float f; } c; c.i = ((u32)u) << 16; return c.f;
}
__device__ __forceinline__ float sigmf(float x) {
  return 1.0f / (1.0f + __expf(-x));
}
__device__ __forceinline__ float tanhff(float x) {
  float a = __expf(2.0f * x);          // inf -> 1, 0 -> -1 : graceful
  return 1.0f - 2.0f / (a + 1.0f);
}

// ---------------- f32 -> bf16 convert ----------------
__global__ __launch_bounds__(256) void cvt_bf16(const float* __restrict__ in,
                                                u16* __restrict__ out, int n8) {
  int i = blockIdx.x * 256 + threadIdx.x;
  if (i >= n8) return;
  const float4* p = (const float4*)in;
  float4 a = p[2*i], b = p[2*i+1];
  union { short8 v; u16 u[8]; } o;
  o.u[0]=f2bf(a.x); o.u[1]=f2bf(a.y); o.u[2]=f2bf(a.z); o.u[3]=f2bf(a.w);
  o.u[4]=f2bf(b.x); o.u[5]=f2bf(b.y); o.u[6]=f2bf(b.z); o.u[7]=f2bf(b.w);
  ((short8*)out)[i] = o.v;
}

// ---------------- gx GEMM (unchanged) ----------------
__global__ __launch_bounds__(256) void gemm_gx(const u16* __restrict__ A,
                                               const u16* __restrict__ Bw,
                                               char* __restrict__ gxout,
                                               int K, int gxf32) {
  __shared__ __align__(16) u16 lA[128*32];
  __shared__ __align__(16) u16 lB[128*32];
  const int tid = threadIdx.x;
  const int lane = tid & 63;
  const int wid = tid >> 6;
  const int wr = wid >> 1, wc = wid & 1;
  const int bm = blockIdx.y * 128, bn = blockIdx.x * 128;
  const int col = lane & 15, kg = lane >> 4;

  f32x4 acc[4][4];
#pragma unroll
  for (int m = 0; m < 4; ++m)
#pragma unroll
    for (int n = 0; n < 4; ++n) acc[m][n] = (f32x4){0.f,0.f,0.f,0.f};

  const int nkt = K >> 5;
  for (int kt = 0; kt < nkt; ++kt) {
    short8 ra[2], rb[2];
    const int kb = kt * 32;
#pragma unroll
    for (int p = 0; p < 2; ++p) {
      int id = p*256 + tid;
      int row = id >> 2, c = id & 3;
      ra[p] = *(const short8*)(A  + (size_t)(bm+row)*K + kb + c*8);
      rb[p] = *(const short8*)(Bw + (size_t)(bn+row)*K + kb + c*8);
    }
    __syncthreads();
#pragma unroll
    for (int p = 0; p < 2; ++p) {
      int id = p*256 + tid;
      int row = id >> 2, c = id & 3;
      int off = row*64 + ((c ^ ((row>>1)&3))*16);
      *(short8*)((char*)lA + off) = ra[p];
      *(short8*)((char*)lB + off) = rb[p];
    }
    __syncthreads();
    short8 af[4], bf[4];
#pragma unroll
    for (int m = 0; m < 4; ++m) {
      int row = wr*64 + m*16 + col;
      af[m] = *(short8*)((char*)lA + row*64 + ((kg ^ ((row>>1)&3))*16));
    }
#pragma unroll
    for (int n = 0; n < 4; ++n) {
      int row = wc*64 + n*16 + col;
      bf[n] = *(short8*)((char*)lB + row*64 + ((kg ^ ((row>>1)&3))*16));
    }
#pragma unroll
    for (int m = 0; m < 4; ++m)
#pragma unroll
      for (int n = 0; n < 4; ++n)
        acc[m][n] = __builtin_amdgcn_mfma_f32_16x16x32_bf16(af[m], bf[n], acc[m][n], 0,0,0);
  }
#pragma unroll
  for (int m = 0; m < 4; ++m)
#pragma unroll
    for (int n = 0; n < 4; ++n)
#pragma unroll
      for (int r = 0; r < 4; ++r) {
        int rowg = bm + wr*64 + m*16 + kg*4 + r;
        int colg = bn + wc*64 + n*16 + col;
        float v = acc[m][n][r];
        if (gxf32) ((float*)gxout)[(size_t)rowg*NG + colg] = v;
        else       ((u16*)gxout)[(size_t)rowg*NG + colg] = f2bf(v);
      }
}

// ---------------- persistent BiGRU recurrence (R14 best configuration) --------
// grid = 32 WGs (512 thr, 8 waves): dir = wg>>4, jb = wg&15 -> cols [jb*32,+32).
// Wave w polls producers p=w and p=w+8 individually (dependent spin — R16 showed
// speculative pipelined polls regress) and reads each 2KB slice when its flag
// lands (sched_barrier+memory clobber pins loads after poll). Plain cached out
// stores (R14 win: NT store HBM-ack stalled next poll via in-order vmcnt).
// Parallel per-wave drain -> LDS counter -> 8th wave releases the WG flag.
__global__ __launch_bounds__(512, 2) void bigru_rec(const char* __restrict__ gx,
                                                    const u16* __restrict__ whhb,
                                                    const float* __restrict__ b_ih,
                                                    const float* __restrict__ b_hh,
                                                    char* __restrict__ out,
                                                    u16* __restrict__ himg,   // [2][2][32][512]
                                                    u32* __restrict__ flags,  // [2][16] stride 16 dwords
                                                    int gxf32, int outf32) {
  const int wg = blockIdx.x;
  const int dir = wg >> 4;
  const int jb = wg & 15;
  const int tid = threadIdx.x;
  const int lane = tid & 63;
  const int wv = tid >> 6;
  const int col = lane & 15, kg = lane >> 4;

  __shared__ __align__(16) u16 hstage[32*512];     // 32 KB, swizzled
  __shared__ float gh[3][32][33];                  // padded: no bank conflicts
  __shared__ float bihs[3][32], bhhs[3][32];
  __shared__ u32 lctr;

  // --- one-time: w_hh B-fragments (waves 0..5: gate g=wv>>1, half ch=wv&1) ---
  short8 bfrag[16];
  if (wv < 6) {
    const int g = wv >> 1, ch = wv & 1;
    const u16* wrow = whhb + (size_t)(dir*1536 + g*512 + jb*CPW + ch*16 + col) * 512;
#pragma unroll
    for (int kc = 0; kc < 16; ++kc)
      bfrag[kc] = *(const short8*)(wrow + kc*32 + kg*8);
  }
  if (tid < 96) {
    int g = tid >> 5, j = tid & 31;
    bihs[g][j] = b_ih[dir*1536 + g*512 + jb*CPW + j];
    bhhs[g][j] = b_hh[dir*1536 + g*512 + jb*CPW + j];
  }
  if (tid == 0) lctr = 0;
  __syncthreads();

  const int gb = tid >> 4, gj0 = (tid & 15) * 2;
  float hp0 = 0.f, hp1 = 0.f;

  u32* dirflags = flags + (size_t)dir * WGD * 16;
  u32* myflag = dirflags + (size_t)jb * 16;

  // slice-read lane mapping: row = lane>>1, 32B group g4 = (lane&1)*4
  const int srow = lane >> 1, sg4 = (lane & 1) * 4;
  const int p0 = wv, p1 = wv + 8;
  const u32* fp0 = dirflags + (size_t)p0 * 16;
  const u32* fp1 = dirflags + (size_t)p1 * 16;

  for (int t = 0; t < TT; ++t) {
    const int tt = dir ? (TT - 1 - t) : t;
    const int par = t & 1;

    // --- gx[tt] -> registers (issued early; retire under poll) ---
    f32x2 xrF, xzF, xnF; u32 xrB=0, xzB=0, xnB=0;
    if (gxf32) {
      const float* gp = (const float*)gx + (size_t)(gb*TT+tt)*NG + dir*1536 + jb*CPW + gj0;
      xrF = *(const f32x2*)(gp);
      xzF = *(const f32x2*)(gp + 512);
      xnF = *(const f32x2*)(gp + 1024);
    } else {
      const u16* gp = (const u16*)gx + (size_t)(gb*TT+tt)*NG + dir*1536 + jb*CPW + gj0;
      xrB = *(const u32*)(gp);
      xzB = *(const u32*)(gp + 512);
      xnB = *(const u32*)(gp + 1024);
    }

    // --- pipelined per-producer poll + slice read (2KB each) ---
    const u64* imgr = (const u64*)(himg + ((size_t)dir*2 + par) * 32 * 512);
    u64 v0[4], v1[4];
    if (t > 0) {
      const u32 need = (u32)t;
      int it = 0;
      while (__hip_atomic_load(fp0, __ATOMIC_RELAXED, __HIP_MEMORY_SCOPE_AGENT) < need && it++ < (1<<24)) {}
    }
    __builtin_amdgcn_sched_barrier(0);
    asm volatile("" ::: "memory");   // pin slice loads AFTER the poll (compiler fence)
#pragma unroll
    for (int j = 0; j < 4; ++j)
      v0[j] = __hip_atomic_load(imgr + srow*128 + p0*8 + sg4 + j, __ATOMIC_RELAXED, __HIP_MEMORY_SCOPE_AGENT);
    if (t > 0) {
      const u32 need = (u32)t;
      int it = 0;
      while (__hip_atomic_load(fp1, __ATOMIC_RELAXED, __HIP_MEMORY_SCOPE_AGENT) < need && it++ < (1<<24)) {}
    }
    __builtin_amdgcn_sched_barrier(0);
    asm volatile("" ::: "memory");   // pin slice loads AFTER the poll (compiler fence)
#pragma unroll
    for (int j = 0; j < 4; ++j)
      v1[j] = __hip_atomic_load(imgr + srow*128 + p1*8 + sg4 + j, __ATOMIC_RELAXED, __HIP_MEMORY_SCOPE_AGENT);

    // --- LDS writes: slices (swizzled) ---
#pragma unroll
    for (int j = 0; j < 4; ++j) {
      int d2 = p0*8 + sg4 + j; int c = d2 >> 1;
      *(u64*)((char*)hstage + srow*1024 + (((c ^ (srow & 7)) << 4) | ((d2 & 1) << 3))) = v0[j];
    }
#pragma unroll
    for (int j = 0; j < 4; ++j) {
      int d2 = p1*8 + sg4 + j; int c = d2 >> 1;
      *(u64*)((char*)hstage + srow*1024 + (((c ^ (srow & 7)) << 4) | ((d2 & 1) << 3))) = v1[j];
    }
    __syncthreads();   // (B) hstage staged by all waves

    // --- MFMA: gh[g][b][jloc] over K=512 (waves 0..5) ---
    if (wv < 6) {
      const int g = wv >> 1, ch = wv & 1;
      f32x4 acc0 = (f32x4){0.f,0.f,0.f,0.f};
      f32x4 acc1 = (f32x4){0.f,0.f,0.f,0.f};
#pragma unroll
      for (int kc = 0; kc < 16; ++kc) {
        int c = kc*4 + kg;
        short8 a0 = *(short8*)((char*)hstage + col*1024      + ((c ^ (col & 7)) << 4));
        short8 a1 = *(short8*)((char*)hstage + (16+col)*1024 + ((c ^ (col & 7)) << 4));
        acc0 = __builtin_amdgcn_mfma_f32_16x16x32_bf16(a0, bfrag[kc], acc0, 0,0,0);
        acc1 = __builtin_amdgcn_mfma_f32_16x16x32_bf16(a1, bfrag[kc], acc1, 0,0,0);
      }
#pragma unroll
      for (int r = 0; r < 4; ++r) {
        gh[g][kg*4 + r][ch*16 + col]      = acc0[r];
        gh[g][16 + kg*4 + r][ch*16 + col] = acc1[r];
      }
    }
    __syncthreads();   // (C)

    // --- gates: thread -> (b=gb, j=gj0, gj0+1) ---
    float hv0, hv1; u32 pv;
    {
      float xr0, xz0, xn0, xr1, xz1, xn1;
      if (gxf32) {
        xr0 = xrF.x; xz0 = xzF.x; xn0 = xnF.x;
        xr1 = xrF.y; xz1 = xzF.y; xn1 = xnF.y;
      } else {
        xr0 = bf2f((u16)(xrB & 0xffff)); xz0 = bf2f((u16)(xzB & 0xffff)); xn0 = bf2f((u16)(xnB & 0xffff));
        xr1 = bf2f((u16)(xrB >> 16));    xz1 = bf2f((u16)(xzB >> 16));    xn1 = bf2f((u16)(xnB >> 16));
      }
      float r0 = sigmf(xr0 + bihs[0][gj0]   + gh[0][gb][gj0]   + bhhs[0][gj0]);
      float z0 = sigmf(xz0 + bihs[1][gj0]   + gh[1][gb][gj0]   + bhhs[1][gj0]);
      float n0 = tanhff(xn0 + bihs[2][gj0]  + r0*(gh[2][gb][gj0] + bhhs[2][gj0]));
      hv0 = (1.f - z0)*n0 + z0*hp0;
      float r1 = sigmf(xr1 + bihs[0][gj0+1] + gh[0][gb][gj0+1] + bhhs[0][gj0+1]);
      float z1 = sigmf(xz1 + bihs[1][gj0+1] + gh[1][gb][gj0+1] + bhhs[1][gj0+1]);
      float n1 = tanhff(xn1 + bihs[2][gj0+1] + r1*(gh[2][gb][gj0+1] + bhhs[2][gj0+1]));
      hv1 = (1.f - z1)*n1 + z1*hp1;
      hp0 = hv0; hp1 = hv1;

      // publish h_new pair to next image (agent -> LLC)
      u32* img2 = (u32*)(himg + ((size_t)dir*2 + ((t + 1) & 1)) * 32 * 512);
      pv = (u32)f2bf(hv0) | ((u32)f2bf(hv1) << 16);
      __hip_atomic_store(img2 + gb*256 + jb*16 + (tid & 15), pv,
                         __ATOMIC_RELAXED, __HIP_MEMORY_SCOPE_AGENT);
    }

    // --- per-wave drain (parallel) -> LDS counter -> 8th wave releases WG flag ---
    asm volatile("s_waitcnt vmcnt(0)" ::: "memory");
    if (lane == 0) {
      u32 old = atomicAdd(&lctr, 1u);
      if (old == (u32)(t*8 + 7))
        __hip_atomic_store(myflag, (u32)(t + 1), __ATOMIC_RELAXED, __HIP_MEMORY_SCOPE_AGENT);
    }

    // --- out store after flag: plain cached store (L2 ack; R14 win) ---
    {
      size_t oi = (size_t)(gb*TT + tt)*1024 + dir*512 + jb*CPW + gj0;
      if (outf32) {
        f32x2 ov; ov.x = hv0; ov.y = hv1;
        *(f32x2*)((float*)out + oi) = ov;
      } else {
        *(u32*)((u16*)out + oi) = pv;
      }
    }
  }
}

// ---------------- host ----------------
extern "C" void kernel_launch(void* const* d_in, const int* in_sizes, int n_in,
                              void* d_out, int out_size, void* d_ws, size_t ws_size,
                              hipStream_t stream) {
  (void)in_sizes; (void)n_in; (void)out_size;
  const float* x    = (const float*)d_in[0];
  const float* wih0 = (const float*)d_in[1];
  const float* whh0 = (const float*)d_in[2];
  const float* bih0 = (const float*)d_in[3];
  const float* bhh0 = (const float*)d_in[4];
  const float* wih1 = (const float*)d_in[5];
  const float* whh1 = (const float*)d_in[6];
  const float* bih1 = (const float*)d_in[7];
  const float* bhh1 = (const float*)d_in[8];

  char* ws = (char*)d_ws;
  size_t off = 0;
  auto alloc = [&](size_t bytes) { size_t o = off; off += (bytes + 255) & ~(size_t)255; return o; };
  size_t off_xb   = alloc((size_t)MM * 512 * 2);       // x bf16
  size_t off_wih0 = alloc((size_t)3072 * 512 * 2);
  size_t off_wih1 = alloc((size_t)3072 * 1024 * 2);
  size_t off_whh0 = alloc((size_t)3072 * 512 * 2);
  size_t off_whh1 = alloc((size_t)3072 * 512 * 2);
  size_t off_h0   = alloc((size_t)MM * 1024 * 2);      // layer-0 output bf16
  size_t off_sync = alloc(131072 + 4096);              // h images (128KB) + flags
  size_t off_gx   = off;                               // gx last
  int gxf32 = (ws_size >= off_gx + (size_t)MM * NG * 4) ? 1 : 0;

  u16* xb    = (u16*)(ws + off_xb);
  u16* wih0b = (u16*)(ws + off_wih0);
  u16* wih1b = (u16*)(ws + off_wih1);
  u16* whh0b = (u16*)(ws + off_whh0);
  u16* whh1b = (u16*)(ws + off_whh1);
  u16* h0b   = (u16*)(ws + off_h0);
  u16* himg  = (u16*)(ws + off_sync);
  u32* flags = (u32*)(ws + off_sync + 131072);
  char* gx   = ws + off_gx;

  cvt_bf16<<<4096, 256, 0, stream>>>(x,    xb,    MM*512/8);
  cvt_bf16<<<768,  256, 0, stream>>>(wih0, wih0b, 3072*512/8);
  cvt_bf16<<<1536, 256, 0, stream>>>(wih1, wih1b, 3072*1024/8);
  cvt_bf16<<<768,  256, 0, stream>>>(whh0, whh0b, 3072*512/8);
  cvt_bf16<<<768,  256, 0, stream>>>(whh1, whh1b, 3072*512/8);

  dim3 ggrid(NG/128, MM/128);   // (24, 128)

  // layer 0
  gemm_gx<<<ggrid, 256, 0, stream>>>(xb, wih0b, gx, 512, gxf32);
  (void)hipMemsetAsync(ws + off_sync, 0, 131072 + 4096, stream);
  bigru_rec<<<32, 512, 0, stream>>>(gx, whh0b, bih0, bhh0, (char*)h0b, himg, flags, gxf32, 0);

  // layer 1
  gemm_gx<<<ggrid, 256, 0, stream>>>(h0b, wih1b, gx, 1024, gxf32);
  (void)hipMemsetAsync(ws + off_sync, 0, 131072 + 4096, stream);
  bigru_rec<<<32, 512, 0, stream>>>(gx, whh1b, bih1, bhh1, (char*)d_out, himg, flags, gxf32, 1);
}